// Round 1
// baseline (161.085 us; speedup 1.0000x reference)
//
#include <hip/hip_runtime.h>
#include <hip/hip_bf16.h>

typedef __bf16 bf16x8 __attribute__((ext_vector_type(8)));
typedef __bf16 bf16x4 __attribute__((ext_vector_type(4)));
typedef float  floatx4 __attribute__((ext_vector_type(4)));

#define B_    4096
#define D_    1024
#define C_    1000
#define CPAD  1024
#define NCOL  (B_ + CPAD)   // 5120
#define TAU_INV 10.0f
#define EPS_    1e-8f

// ---------------- init: zero accumulators, counts, center pad rows ----------
__global__ void init_kernel(float* denom, float* possum, int* counts, __bf16* cpad) {
    int i = blockIdx.x * 256 + threadIdx.x;            // grid 16 x 256 = 4096
    if (i < B_) { denom[i] = 0.f; possum[i] = 0.f; }
    if (i < CPAD) counts[i] = 0;
    for (int j = i; j < (CPAD - C_) * D_; j += 4096) cpad[j] = (__bf16)0.f;
}

__global__ void count_kernel(const int* __restrict__ targets, int* counts) {
    int i = blockIdx.x * 256 + threadIdx.x;
    if (i < B_) atomicAdd(&counts[targets[i]], 1);
}

__global__ void wcol_kernel(const int* __restrict__ counts, const int* __restrict__ targets,
                            float* __restrict__ wcol) {
    int i = blockIdx.x * 256 + threadIdx.x;            // grid 20 x 256 = 5120
    if (i >= NCOL) return;
    if (i < B_) {
        wcol[i] = 1.f / (float)(counts[targets[i]] + 1);
    } else {
        int j = i - B_;
        wcol[i] = (j < C_) ? 1.f / (float)(counts[j] + 1) : 0.f;
    }
}

// ---------------- fp32 -> bf16 conversion (vectorized x4) -------------------
__global__ void cvt_kernel(const float* __restrict__ src, __bf16* __restrict__ dst, int n4) {
    int i = blockIdx.x * 256 + threadIdx.x;
    if (i < n4) {
        float4 v = ((const float4*)src)[i];
        bf16x4 o;
        o[0] = (__bf16)v.x; o[1] = (__bf16)v.y; o[2] = (__bf16)v.z; o[3] = (__bf16)v.w;
        ((bf16x4*)dst)[i] = o;
    }
}

// ---------------- fused GEMM + epilogue -------------------------------------
// sims[i,k] = dot(F[i], Bcat[k]) / tau ; Bcat = [features(4096 rows); centers padded to 1024 rows]
// denom[i]  += sum_k wcol[k] * exp(sims[i,k])
// possum[i] += sum_{k: class(k)==class(i), k != i} log(exp(sims[i,k]) + eps)   (incl. center term)
#define GLD_LDS16(g, l) __builtin_amdgcn_global_load_lds( \
    (const __attribute__((address_space(1))) void*)(g),   \
    (__attribute__((address_space(3))) void*)(l), 16, 0, 0)

__global__ __launch_bounds__(256) void gemm_epilogue(
    const __bf16* __restrict__ Abf,   // [4096][1024]
    const __bf16* __restrict__ Cbf,   // [1024][1024]
    const float*  __restrict__ wcol,  // [5120]
    const int*    __restrict__ targets,
    float* __restrict__ denom, float* __restrict__ possum)
{
    __shared__ __align__(16) __bf16 ldsA[128 * 32];
    __shared__ __align__(16) __bf16 ldsB[128 * 32];

    const int tid  = threadIdx.x;
    const int wave = tid >> 6;
    const int lane = tid & 63;

    const int rowTile = (blockIdx.x & 31) * 128;      // 32 row tiles
    const int colIdx  = blockIdx.x >> 5;              // 40 col tiles
    const int colTile = colIdx * 128;

    const __bf16* Bbase = (colIdx < 32) ? (Abf + (size_t)colIdx * 128 * D_)
                                        : (Cbf + (size_t)(colIdx - 32) * 128 * D_);

    // staging: 128x32 bf16 = 8192 B per tile; 256 thr x 16 B = 4096 B/round, 2 rounds
    const int c0 = tid;                                // chunk id round 0; round1 = c0+256
    const __bf16* gA0 = Abf   + (size_t)(rowTile + (c0 >> 2)) * D_ + (c0 & 3) * 8;
    const __bf16* gA1 = gA0 + (size_t)64 * D_;
    const __bf16* gB0 = Bbase + (size_t)(c0 >> 2) * D_ + (c0 & 3) * 8;
    const __bf16* gB1 = gB0 + (size_t)64 * D_;
    __bf16* lA0 = &ldsA[(0 * 4 + wave) * 512];
    __bf16* lA1 = &ldsA[(1 * 4 + wave) * 512];
    __bf16* lB0 = &ldsB[(0 * 4 + wave) * 512];
    __bf16* lB1 = &ldsB[(1 * 4 + wave) * 512];

    floatx4 acc[4][4] = {};

    const int wrow  = (wave >> 1) * 64;   // wave's 64x64 subtile
    const int wcolw = (wave & 1) * 64;
    const int fr = lane & 15;
    const int fq = lane >> 4;

    for (int k0 = 0; k0 < D_; k0 += 32) {
        if (k0) __syncthreads();
        GLD_LDS16(gA0 + k0, lA0);
        GLD_LDS16(gA1 + k0, lA1);
        GLD_LDS16(gB0 + k0, lB0);
        GLD_LDS16(gB1 + k0, lB1);
        __syncthreads();   // drains vmcnt (lds-DMA) + barrier

        bf16x8 af[4], bfv[4];
        #pragma unroll
        for (int ri = 0; ri < 4; ++ri)
            af[ri] = *(const bf16x8*)&ldsA[(wrow + ri * 16 + fr) * 32 + fq * 8];
        #pragma unroll
        for (int ci = 0; ci < 4; ++ci)
            bfv[ci] = *(const bf16x8*)&ldsB[(wcolw + ci * 16 + fr) * 32 + fq * 8];
        #pragma unroll
        for (int ri = 0; ri < 4; ++ri)
            #pragma unroll
            for (int ci = 0; ci < 4; ++ci)
                acc[ri][ci] = __builtin_amdgcn_mfma_f32_16x16x32_bf16(af[ri], bfv[ci], acc[ri][ci], 0, 0, 0);
    }

    // ---- epilogue: weighted exp-sums + positive log-sums, per row ----
    float wv[4]; int tcol[4]; int colg[4];
    #pragma unroll
    for (int ci = 0; ci < 4; ++ci) {
        int cg = colTile + wcolw + ci * 16 + fr;
        colg[ci] = cg;
        wv[ci]   = wcol[cg];
        tcol[ci] = (cg < B_) ? targets[cg] : (cg - B_);   // padded cols give class >= C_, never matches
    }
    #pragma unroll
    for (int ri = 0; ri < 4; ++ri) {
        #pragma unroll
        for (int reg = 0; reg < 4; ++reg) {
            int rowg = rowTile + wrow + ri * 16 + fq * 4 + reg;   // C/D layout: row=(lane>>4)*4+reg
            int trow = targets[rowg];
            float dsum = 0.f, psum = 0.f;
            #pragma unroll
            for (int ci = 0; ci < 4; ++ci) {
                float s = acc[ri][ci][reg] * TAU_INV;
                float e = __expf(s);
                dsum += wv[ci] * e;
                if (tcol[ci] == trow && colg[ci] != rowg)
                    psum += s + log1pf(EPS_ * __expf(-s));   // = log(exp(s)+eps)
            }
            #pragma unroll
            for (int m = 1; m < 16; m <<= 1) {
                dsum += __shfl_xor(dsum, m, 64);
                psum += __shfl_xor(psum, m, 64);
            }
            if (fr == 0) {
                atomicAdd(&denom[rowg],  dsum);
                atomicAdd(&possum[rowg], psum);
            }
        }
    }
}

// ---------------- finalize: per-sample loss -> mean -------------------------
__global__ void finalize_kernel(const float* __restrict__ denom, const float* __restrict__ possum,
                                const int* __restrict__ counts, const int* __restrict__ targets,
                                float* __restrict__ out) {
    __shared__ float red[4];
    float local = 0.f;
    for (int i = threadIdx.x; i < B_; i += 256) {
        float npos = (float)counts[targets[i]];
        local += logf(denom[i] + EPS_) - possum[i] / npos;
    }
    #pragma unroll
    for (int m = 1; m < 64; m <<= 1) local += __shfl_xor(local, m, 64);
    int w = threadIdx.x >> 6;
    if ((threadIdx.x & 63) == 0) red[w] = local;
    __syncthreads();
    if (threadIdx.x == 0) out[0] = (red[0] + red[1] + red[2] + red[3]) * (1.f / (float)B_);
}

extern "C" void kernel_launch(void* const* d_in, const int* in_sizes, int n_in,
                              void* d_out, int out_size, void* d_ws, size_t ws_size,
                              hipStream_t stream) {
    const float* centers  = (const float*)d_in[0];   // [1000][1024]
    const float* features = (const float*)d_in[1];   // [4096][1024]
    const int*   targets  = (const int*)d_in[2];     // [4096]
    float* out = (float*)d_out;

    char* ws = (char*)d_ws;
    __bf16* Abf   = (__bf16*)(ws);                         // 8 MiB
    __bf16* Cbf   = (__bf16*)(ws + 8388608);               // 2 MiB (1024 rows, 24 zero-padded)
    float*  wcol  = (float*) (ws + 10485760);              // 5120 f32
    int*    counts= (int*)   (ws + 10506240);              // 1024 i32
    float*  denom = (float*) (ws + 10510336);              // 4096 f32
    float*  possum= (float*) (ws + 10526720);              // 4096 f32

    hipLaunchKernelGGL(init_kernel,  dim3(16),   dim3(256), 0, stream, denom, possum, counts, Cbf + C_ * D_);
    hipLaunchKernelGGL(count_kernel, dim3(16),   dim3(256), 0, stream, targets, counts);
    hipLaunchKernelGGL(cvt_kernel,   dim3(4096), dim3(256), 0, stream, features, Abf, (B_ * D_) / 4);
    hipLaunchKernelGGL(cvt_kernel,   dim3(1000), dim3(256), 0, stream, centers, Cbf, (C_ * D_) / 4);
    hipLaunchKernelGGL(wcol_kernel,  dim3(20),   dim3(256), 0, stream, counts, targets, wcol);
    hipLaunchKernelGGL(gemm_epilogue, dim3(32 * 40), dim3(256), 0, stream, Abf, Cbf, wcol, targets, denom, possum);
    hipLaunchKernelGGL(finalize_kernel, dim3(1), dim3(256), 0, stream, denom, possum, counts, targets, out);
}

// Round 3
// 156.143 us; speedup vs baseline: 1.0316x; 1.0316x over previous
//
#include <hip/hip_runtime.h>
#include <hip/hip_bf16.h>

typedef __bf16 bf16x8 __attribute__((ext_vector_type(8)));
typedef __bf16 bf16x4 __attribute__((ext_vector_type(4)));
typedef float  floatx4 __attribute__((ext_vector_type(4)));

#define B_    4096
#define D_    1024
#define C_    1000
#define CPAD  1024
#define NVALID (B_ + C_)    // 5096 valid columns
#define TAU_INV 10.0f
#define EPS_    1e-8f

// ---------------- prep: cvt fp32->bf16, zero accum + pad, class counts ------
// grid 5117 x 256. Work map (g = global thread):
//   [0, 1048576)         : features cvt, float4 #g            (4096*1024/4)
//   [1048576, 1304576)   : centers  cvt, float4 #(g-1048576)  (1000*1024/4)
//   [1304576, 1306624)   : zero denom(1024 f4) then possum(1024 f4)
//   [1306624, 1309696)   : zero center pad rows, int4 (24*1024*2B = 49152 B)
// block 5116 (g >= 1309696, idle above) computes counts[1024] via LDS atomics.
__global__ __launch_bounds__(256) void prep_kernel(
    const float* __restrict__ centers, const float* __restrict__ features,
    const int* __restrict__ targets,
    __bf16* __restrict__ Abf, __bf16* __restrict__ Cbf,
    float* __restrict__ denom, float* __restrict__ possum, int* __restrict__ counts)
{
    const int tid = threadIdx.x;
    const int g = blockIdx.x * 256 + tid;
    if (g < 1048576) {
        float4 v = ((const float4*)features)[g];
        bf16x4 o; o[0] = (__bf16)v.x; o[1] = (__bf16)v.y; o[2] = (__bf16)v.z; o[3] = (__bf16)v.w;
        ((bf16x4*)Abf)[g] = o;
    } else if (g < 1304576) {
        int i = g - 1048576;
        float4 v = ((const float4*)centers)[i];
        bf16x4 o; o[0] = (__bf16)v.x; o[1] = (__bf16)v.y; o[2] = (__bf16)v.z; o[3] = (__bf16)v.w;
        ((bf16x4*)Cbf)[i] = o;
    } else if (g < 1306624) {
        int i = g - 1304576;                    // 0..2047
        float4 z = make_float4(0.f, 0.f, 0.f, 0.f);
        if (i < 1024) ((float4*)denom)[i] = z;
        else          ((float4*)possum)[i - 1024] = z;
    } else if (g < 1309696) {
        int i = g - 1306624;                    // 0..3071
        int4 z = make_int4(0, 0, 0, 0);
        ((int4*)(Cbf + (size_t)C_ * D_))[i] = z;
    }
    if (blockIdx.x == 5116) {
        __shared__ int lc[CPAD];
        #pragma unroll
        for (int j = 0; j < 4; ++j) lc[tid * 4 + j] = 0;
        __syncthreads();
        for (int i = tid; i < B_; i += 256) atomicAdd(&lc[targets[i]], 1);
        __syncthreads();
        int4 o; o.x = lc[tid*4]; o.y = lc[tid*4+1]; o.z = lc[tid*4+2]; o.w = lc[tid*4+3];
        ((int4*)counts)[tid] = o;
    }
}

// ---------------- fused symmetric GEMM + dual-sided epilogue ----------------
// Tiles: bid < 528  -> symmetric F.F^T pair (rt <= ct), mirror if rt != ct
//        bid >= 528 -> center tiles: rt = m>>3, col block m&7 of Cbf
#define GLD_LDS16(g, l) __builtin_amdgcn_global_load_lds( \
    (const __attribute__((address_space(1))) void*)(g),   \
    (__attribute__((address_space(3))) void*)(l), 16, 0, 0)

__global__ __launch_bounds__(256) void gemm_epilogue(
    const __bf16* __restrict__ Abf,   // [4096][1024]
    const __bf16* __restrict__ Cbf,   // [1024][1024] (rows >= 1000 zero)
    const int*    __restrict__ counts,
    const int*    __restrict__ targets,
    float* __restrict__ denom, float* __restrict__ possum)
{
    __shared__ __align__(16) __bf16 ldsA[128 * 32];
    __shared__ __align__(16) __bf16 ldsB[128 * 32];

    const int tid  = threadIdx.x;
    const int wave = tid >> 6;
    const int lane = tid & 63;
    const int bid  = blockIdx.x;

    int rt, colTile;
    const __bf16* Bbase;
    bool mirror;
    if (bid < 528) {
        int idx = bid, r = 0;
        while (idx >= 32 - r) { idx -= 32 - r; ++r; }   // scalar, uniform
        rt = r;
        int ct = r + idx;
        colTile = ct * 128;
        Bbase = Abf + (size_t)ct * 128 * D_;
        mirror = (ct != rt);
    } else {
        int m = bid - 528;
        rt = m >> 3;
        int cc = m & 7;
        colTile = B_ + cc * 128;
        Bbase = Cbf + (size_t)cc * 128 * D_;
        mirror = false;
    }
    const int rowTile = rt * 128;

    // staging: 128x32 bf16 = 8 KiB/tile; 256 thr x 16 B = 4 KiB/round, 2 rounds
    const int c0 = tid;
    const __bf16* gA0 = Abf   + (size_t)(rowTile + (c0 >> 2)) * D_ + (c0 & 3) * 8;
    const __bf16* gA1 = gA0 + (size_t)64 * D_;
    const __bf16* gB0 = Bbase + (size_t)(c0 >> 2) * D_ + (c0 & 3) * 8;
    const __bf16* gB1 = gB0 + (size_t)64 * D_;
    __bf16* lA0 = &ldsA[(0 * 4 + wave) * 512];
    __bf16* lA1 = &ldsA[(1 * 4 + wave) * 512];
    __bf16* lB0 = &ldsB[(0 * 4 + wave) * 512];
    __bf16* lB1 = &ldsB[(1 * 4 + wave) * 512];

    floatx4 acc[4][4] = {};

    const int wrow  = (wave >> 1) * 64;
    const int wcolw = (wave & 1) * 64;
    const int fr = lane & 15;
    const int fq = lane >> 4;

    for (int k0 = 0; k0 < D_; k0 += 32) {
        if (k0) __syncthreads();
        GLD_LDS16(gA0 + k0, lA0);
        GLD_LDS16(gA1 + k0, lA1);
        GLD_LDS16(gB0 + k0, lB0);
        GLD_LDS16(gB1 + k0, lB1);
        __syncthreads();

        bf16x8 af[4], bfv[4];
        #pragma unroll
        for (int ri = 0; ri < 4; ++ri)
            af[ri] = *(const bf16x8*)&ldsA[(wrow + ri * 16 + fr) * 32 + fq * 8];
        #pragma unroll
        for (int ci = 0; ci < 4; ++ci)
            bfv[ci] = *(const bf16x8*)&ldsB[(wcolw + ci * 16 + fr) * 32 + fq * 8];
        #pragma unroll
        for (int ri = 0; ri < 4; ++ri)
            #pragma unroll
            for (int ci = 0; ci < 4; ++ci)
                acc[ri][ci] = __builtin_amdgcn_mfma_f32_16x16x32_bf16(af[ri], bfv[ci], acc[ri][ci], 0, 0, 0);
    }

    // ---- epilogue ----
    float wv[4]; int tcol[4]; int colg[4];
    #pragma unroll
    for (int ci = 0; ci < 4; ++ci) {
        int cg = colTile + wcolw + ci * 16 + fr;
        colg[ci] = cg;
        int cls = (cg < B_) ? targets[cg] : (cg - B_);
        tcol[ci] = cls;
        wv[ci] = (cg < NVALID) ? 1.f / (float)(counts[cls] + 1) : 0.f;
    }

    float dcol[4] = {0.f, 0.f, 0.f, 0.f};
    float pcol[4] = {0.f, 0.f, 0.f, 0.f};

    #pragma unroll
    for (int ri = 0; ri < 4; ++ri) {
        #pragma unroll
        for (int reg = 0; reg < 4; ++reg) {
            int rowg = rowTile + wrow + ri * 16 + fq * 4 + reg;   // C/D: row=(lane>>4)*4+reg
            int trow = targets[rowg];
            float wr = 1.f / (float)(counts[trow] + 1);
            float dsum = 0.f, psum = 0.f;
            #pragma unroll
            for (int ci = 0; ci < 4; ++ci) {
                float s = acc[ri][ci][reg] * TAU_INV;
                float e = __expf(s);
                dsum += wv[ci] * e;
                bool pos = (tcol[ci] == trow) && (colg[ci] != rowg);
                float gterm = pos ? (s + log1pf(EPS_ * __expf(-s))) : 0.f;   // log(exp(s)+eps)
                psum += gterm;
                if (mirror) { dcol[ci] += wr * e; pcol[ci] += gterm; }
            }
            #pragma unroll
            for (int m = 1; m < 16; m <<= 1) {
                dsum += __shfl_xor(dsum, m, 64);
                psum += __shfl_xor(psum, m, 64);
            }
            if (fr == 0) {
                atomicAdd(&denom[rowg],  dsum);
                atomicAdd(&possum[rowg], psum);
            }
        }
    }

    if (mirror) {
        #pragma unroll
        for (int ci = 0; ci < 4; ++ci) {
            float d = dcol[ci], p = pcol[ci];
            d += __shfl_xor(d, 16, 64); d += __shfl_xor(d, 32, 64);
            p += __shfl_xor(p, 16, 64); p += __shfl_xor(p, 32, 64);
            if (fq == 0) {
                atomicAdd(&denom[colg[ci]],  d);
                atomicAdd(&possum[colg[ci]], p);
            }
        }
    }
}

// ---------------- finalize: per-sample loss -> mean -------------------------
__global__ void finalize_kernel(const float* __restrict__ denom, const float* __restrict__ possum,
                                const int* __restrict__ counts, const int* __restrict__ targets,
                                float* __restrict__ out) {
    __shared__ float red[4];
    float local = 0.f;
    for (int i = threadIdx.x; i < B_; i += 256) {
        float npos = (float)counts[targets[i]];
        local += logf(denom[i] + EPS_) - possum[i] / npos;
    }
    #pragma unroll
    for (int m = 1; m < 64; m <<= 1) local += __shfl_xor(local, m, 64);
    int w = threadIdx.x >> 6;
    if ((threadIdx.x & 63) == 0) red[w] = local;
    __syncthreads();
    if (threadIdx.x == 0) out[0] = (red[0] + red[1] + red[2] + red[3]) * (1.f / (float)B_);
}

extern "C" void kernel_launch(void* const* d_in, const int* in_sizes, int n_in,
                              void* d_out, int out_size, void* d_ws, size_t ws_size,
                              hipStream_t stream) {
    const float* centers  = (const float*)d_in[0];   // [1000][1024]
    const float* features = (const float*)d_in[1];   // [4096][1024]
    const int*   targets  = (const int*)d_in[2];     // [4096]
    float* out = (float*)d_out;

    char* ws = (char*)d_ws;
    __bf16* Abf    = (__bf16*)(ws);                        // 8 MiB
    __bf16* Cbf    = (__bf16*)(ws + 8388608);              // 2 MiB (rows 1000..1023 zeroed)
    int*    counts = (int*)   (ws + 10485760);             // 1024 i32
    float*  denom  = (float*) (ws + 10489856);             // 4096 f32
    float*  possum = (float*) (ws + 10506240);             // 4096 f32

    hipLaunchKernelGGL(prep_kernel, dim3(5117), dim3(256), 0, stream,
                       centers, features, targets, Abf, Cbf, denom, possum, counts);
    hipLaunchKernelGGL(gemm_epilogue, dim3(784), dim3(256), 0, stream,
                       Abf, Cbf, counts, targets, denom, possum);
    hipLaunchKernelGGL(finalize_kernel, dim3(1), dim3(256), 0, stream,
                       denom, possum, counts, targets, out);
}

// Round 4
// 145.417 us; speedup vs baseline: 1.1077x; 1.0738x over previous
//
#include <hip/hip_runtime.h>
#include <hip/hip_bf16.h>
#include <hip/hip_fp8.h>
#include <stdint.h>

typedef float floatx4 __attribute__((ext_vector_type(4)));

#define B_    4096
#define D_    1024
#define C_    1000
#define CPAD  1024
#define NVALID (B_ + C_)    // 5096 valid columns
#define TAU_INV 10.0f
#define EPS_    1e-8f

__device__ inline unsigned cvt4_fp8(float4 v) {
    __hip_fp8_e4m3 a(v.x), b(v.y), c(v.z), d(v.w);
    return (unsigned)a.__x | ((unsigned)b.__x << 8) | ((unsigned)c.__x << 16) | ((unsigned)d.__x << 24);
}

// ---------------- prep: cvt fp32->fp8, zero accum + pad, class counts ------
// grid 5111 x 256. Work map (g = global thread):
//   [0, 1048576)         : features cvt, float4 #g -> u32 fp8x4   (4096*1024/4)
//   [1048576, 1304576)   : centers  cvt, float4 #(g-1048576)      (1000*1024/4)
//   [1304576, 1306624)   : zero denom(1024 f4) then possum(1024 f4)
//   [1306624, 1308160)   : zero center pad rows, int4 (24*1024 B = 1536 int4)
// block 5110 (g >= 1308160, idle above) computes counts[1024] via LDS atomics.
__global__ __launch_bounds__(256) void prep_kernel(
    const float* __restrict__ centers, const float* __restrict__ features,
    const int* __restrict__ targets,
    unsigned* __restrict__ Af8, unsigned* __restrict__ Cf8,
    float* __restrict__ denom, float* __restrict__ possum, int* __restrict__ counts)
{
    const int tid = threadIdx.x;
    const int g = blockIdx.x * 256 + tid;
    if (g < 1048576) {
        Af8[g] = cvt4_fp8(((const float4*)features)[g]);
    } else if (g < 1304576) {
        int i = g - 1048576;
        Cf8[i] = cvt4_fp8(((const float4*)centers)[i]);
    } else if (g < 1306624) {
        int i = g - 1304576;                    // 0..2047
        float4 z = make_float4(0.f, 0.f, 0.f, 0.f);
        if (i < 1024) ((float4*)denom)[i] = z;
        else          ((float4*)possum)[i - 1024] = z;
    } else if (g < 1308160) {
        int i = g - 1306624;                    // 0..1535
        int4 z = make_int4(0, 0, 0, 0);
        ((int4*)((uint8_t*)Cf8 + (size_t)C_ * D_))[i] = z;
    }
    if (blockIdx.x == 5110) {
        __shared__ int lc[CPAD];
        #pragma unroll
        for (int j = 0; j < 4; ++j) lc[tid * 4 + j] = 0;
        __syncthreads();
        for (int i = tid; i < B_; i += 256) atomicAdd(&lc[targets[i]], 1);
        __syncthreads();
        int4 o; o.x = lc[tid*4]; o.y = lc[tid*4+1]; o.z = lc[tid*4+2]; o.w = lc[tid*4+3];
        ((int4*)counts)[tid] = o;
    }
}

// ---------------- fused symmetric fp8 GEMM + dual-sided epilogue ------------
// Tiles: bid < 528  -> symmetric F.F^T pair (rt <= ct), mirror if rt != ct
//        bid >= 528 -> center tiles: rt = m>>3, col block m&7 of Cf8
// BK = 64 (fp8, 1 B/elem): ldsA/ldsB 128x64 = 8 KiB each. 16 K-iterations.
// LDS layout XOR-swizzled on 16-B chunks: chunk_slot = kchunk ^ ((row>>1)&3),
// applied on the GLOBAL fetch side so global_load_lds's contiguous 1024-B
// wave-write is preserved; fragment ds_read_b64 then lands at the structural
// 4-dword/bank minimum (conflict-free).
#define GLD_LDS16(g, l) __builtin_amdgcn_global_load_lds( \
    (const __attribute__((address_space(1))) void*)(g),   \
    (__attribute__((address_space(3))) void*)(l), 16, 0, 0)

__global__ __launch_bounds__(256, 4) void gemm_epilogue(
    const uint8_t* __restrict__ Af8,   // [4096][1024] fp8 e4m3
    const uint8_t* __restrict__ Cf8,   // [1024][1024] fp8 (rows >= 1000 zero)
    const int*     __restrict__ counts,
    const int*     __restrict__ targets,
    float* __restrict__ denom, float* __restrict__ possum)
{
    __shared__ __align__(16) uint8_t ldsA[128 * 64];
    __shared__ __align__(16) uint8_t ldsB[128 * 64];

    const int tid  = threadIdx.x;
    const int wave = tid >> 6;
    const int lane = tid & 63;
    const int bid  = blockIdx.x;

    int rt, colTile;
    const uint8_t* Bbase;
    bool mirror;
    if (bid < 528) {
        int idx = bid, r = 0;
        while (idx >= 32 - r) { idx -= 32 - r; ++r; }   // scalar, uniform
        rt = r;
        int ct = r + idx;
        colTile = ct * 128;
        Bbase = Af8 + (size_t)ct * 128 * D_;
        mirror = (ct != rt);
    } else {
        int m = bid - 528;
        rt = m >> 3;
        int cc = m & 7;
        colTile = B_ + cc * 128;
        Bbase = Cf8 + (size_t)cc * 128 * D_;
        mirror = false;
    }
    const int rowTile = rt * 128;

    // ---- staging map: 2 instrs per matrix per thread; instr j covers rows
    // (wave + 4j)*16 .. +15 (lane>>2 within), chunk (lane&3) XOR-permuted.
    const int r0 = wave * 16 + (lane >> 2);         // j = 0 local row
    const int r1 = r0 + 64;                          // j = 1 local row
    const int gc0 = ((lane & 3) ^ ((r0 >> 1) & 3)) * 16;
    const int gc1 = ((lane & 3) ^ ((r1 >> 1) & 3)) * 16;
    const uint8_t* gA0 = Af8 + (size_t)(rowTile + r0) * D_ + gc0;
    const uint8_t* gA1 = Af8 + (size_t)(rowTile + r1) * D_ + gc1;
    const uint8_t* gB0 = Bbase + (size_t)r0 * D_ + gc0;
    const uint8_t* gB1 = Bbase + (size_t)r1 * D_ + gc1;
    uint8_t* lA0 = &ldsA[wave * 1024];
    uint8_t* lA1 = &ldsA[(wave + 4) * 1024];
    uint8_t* lB0 = &ldsB[wave * 1024];
    uint8_t* lB1 = &ldsB[(wave + 4) * 1024];

    floatx4 acc[4][4] = {};

    const int wrow  = (wave >> 1) * 64;
    const int wcolw = (wave & 1) * 64;
    const int fr = lane & 15;
    const int fq = lane >> 4;
    // fragment LDS byte offsets within a row, per k-step s (row>>1 == fr>>1 mod 4
    // since all row bases are multiples of 8):
    const int sw = (fr >> 1) & 3;
    const int off_s0 = (((fq >> 1) ^ sw) * 16) + (fq & 1) * 8;          // s=0: kchunk = fq>>1
    const int off_s1 = (((2 + (fq >> 1)) ^ sw) * 16) + (fq & 1) * 8;    // s=1: kchunk = 2 + fq>>1

    for (int k0 = 0; k0 < D_; k0 += 64) {
        if (k0) __syncthreads();
        GLD_LDS16(gA0 + k0, lA0);
        GLD_LDS16(gA1 + k0, lA1);
        GLD_LDS16(gB0 + k0, lB0);
        GLD_LDS16(gB1 + k0, lB1);
        __syncthreads();

        #pragma unroll
        for (int s = 0; s < 2; ++s) {
            const int off = s ? off_s1 : off_s0;
            long af[4], bfv[4];
            #pragma unroll
            for (int ri = 0; ri < 4; ++ri)
                af[ri] = *(const long*)&ldsA[(wrow + ri * 16 + fr) * 64 + off];
            #pragma unroll
            for (int ci = 0; ci < 4; ++ci)
                bfv[ci] = *(const long*)&ldsB[(wcolw + ci * 16 + fr) * 64 + off];
            #pragma unroll
            for (int ri = 0; ri < 4; ++ri)
                #pragma unroll
                for (int ci = 0; ci < 4; ++ci)
                    acc[ri][ci] = __builtin_amdgcn_mfma_f32_16x16x32_fp8_fp8(
                        af[ri], bfv[ci], acc[ri][ci], 0, 0, 0);
        }
    }

    // ---- epilogue ----
    float wv[4]; int tcol[4]; int colg[4];
    #pragma unroll
    for (int ci = 0; ci < 4; ++ci) {
        int cg = colTile + wcolw + ci * 16 + fr;
        colg[ci] = cg;
        int cls = (cg < B_) ? targets[cg] : (cg - B_);
        tcol[ci] = cls;
        wv[ci] = (cg < NVALID) ? 1.f / (float)(counts[cls] + 1) : 0.f;
    }

    float dcol[4] = {0.f, 0.f, 0.f, 0.f};
    float pcol[4] = {0.f, 0.f, 0.f, 0.f};

    #pragma unroll
    for (int ri = 0; ri < 4; ++ri) {
        #pragma unroll
        for (int reg = 0; reg < 4; ++reg) {
            int rowg = rowTile + wrow + ri * 16 + fq * 4 + reg;   // C/D: row=(lane>>4)*4+reg
            int trow = targets[rowg];
            float wr = 1.f / (float)(counts[trow] + 1);
            float dsum = 0.f, psum = 0.f;
            #pragma unroll
            for (int ci = 0; ci < 4; ++ci) {
                float s = acc[ri][ci][reg] * TAU_INV;
                float e = __expf(s);
                dsum += wv[ci] * e;
                bool pos = (tcol[ci] == trow) && (colg[ci] != rowg);
                float gterm = pos ? (s + log1pf(EPS_ * __expf(-s))) : 0.f;   // log(exp(s)+eps)
                psum += gterm;
                if (mirror) { dcol[ci] += wr * e; pcol[ci] += gterm; }
            }
            #pragma unroll
            for (int m = 1; m < 16; m <<= 1) {
                dsum += __shfl_xor(dsum, m, 64);
                psum += __shfl_xor(psum, m, 64);
            }
            if (fr == 0) {
                atomicAdd(&denom[rowg],  dsum);
                atomicAdd(&possum[rowg], psum);
            }
        }
    }

    if (mirror) {
        #pragma unroll
        for (int ci = 0; ci < 4; ++ci) {
            float d = dcol[ci], p = pcol[ci];
            d += __shfl_xor(d, 16, 64); d += __shfl_xor(d, 32, 64);
            p += __shfl_xor(p, 16, 64); p += __shfl_xor(p, 32, 64);
            if (fq == 0) {
                atomicAdd(&denom[colg[ci]],  d);
                atomicAdd(&possum[colg[ci]], p);
            }
        }
    }
}

// ---------------- finalize: per-sample loss -> mean -------------------------
__global__ void finalize_kernel(const float* __restrict__ denom, const float* __restrict__ possum,
                                const int* __restrict__ counts, const int* __restrict__ targets,
                                float* __restrict__ out) {
    __shared__ float red[4];
    float local = 0.f;
    for (int i = threadIdx.x; i < B_; i += 256) {
        float npos = (float)counts[targets[i]];
        local += logf(denom[i] + EPS_) - possum[i] / npos;
    }
    #pragma unroll
    for (int m = 1; m < 64; m <<= 1) local += __shfl_xor(local, m, 64);
    int w = threadIdx.x >> 6;
    if ((threadIdx.x & 63) == 0) red[w] = local;
    __syncthreads();
    if (threadIdx.x == 0) out[0] = (red[0] + red[1] + red[2] + red[3]) * (1.f / (float)B_);
}

extern "C" void kernel_launch(void* const* d_in, const int* in_sizes, int n_in,
                              void* d_out, int out_size, void* d_ws, size_t ws_size,
                              hipStream_t stream) {
    const float* centers  = (const float*)d_in[0];   // [1000][1024]
    const float* features = (const float*)d_in[1];   // [4096][1024]
    const int*   targets  = (const int*)d_in[2];     // [4096]
    float* out = (float*)d_out;

    char* ws = (char*)d_ws;
    unsigned* Af8   = (unsigned*)(ws);                     // 4 MiB fp8
    unsigned* Cf8   = (unsigned*)(ws + 4194304);           // 1 MiB fp8 (rows 1000..1023 zeroed)
    int*    counts = (int*)   (ws + 5242880);              // 1024 i32
    float*  denom  = (float*) (ws + 5246976);              // 4096 f32
    float*  possum = (float*) (ws + 5263360);              // 4096 f32

    hipLaunchKernelGGL(prep_kernel, dim3(5111), dim3(256), 0, stream,
                       centers, features, targets, Af8, Cf8, denom, possum, counts);
    hipLaunchKernelGGL(gemm_epilogue, dim3(784), dim3(256), 0, stream,
                       (const uint8_t*)Af8, (const uint8_t*)Cf8, counts, targets, denom, possum);
    hipLaunchKernelGGL(finalize_kernel, dim3(1), dim3(256), 0, stream,
                       denom, possum, counts, targets, out);
}